// Round 1
// baseline (1858.424 us; speedup 1.0000x reference)
//
#include <hip/hip_runtime.h>
#include <hip/hip_bf16.h>

constexpr int B = 2, L = 2048, DMODEL = 768, NH = 12, F = 16, DH = 64;
constexpr int NPROJ = 192 + 192 + 768; // 1152

// ---------------- fp32 GEMM: C(MxN) = A(MxK) @ B(KxN), 128x128x8, 256 thr ----
// B is split into up to 3 row-major segments (for [Wq|Wk|Wv]); for a single
// matrix pass s1=s2=N so only B0 is used. Column chunks of 4 never straddle a
// segment boundary (boundaries at 192/384 are multiples of 4).
__global__ __launch_bounds__(256)
void gemm_kernel(const float* __restrict__ A, int M, int N, int K,
                 const float* __restrict__ B0, const float* __restrict__ B1,
                 const float* __restrict__ B2, int s1, int s2,
                 int ld0, int ld1, int ld2, float* __restrict__ C) {
  __shared__ __align__(16) float As[8][128];
  __shared__ __align__(16) float Bs[8][128];
  int tid = threadIdx.x;
  int tx = tid & 15, ty = tid >> 4;
  int m0 = blockIdx.y * 128, n0 = blockIdx.x * 128;
  float acc[8][8] = {};
  int arow = tid >> 1, acol = (tid & 1) * 4;
  int brow = tid >> 5, bcol = (tid & 31) * 4;
  int j = n0 + bcol;
  const float* bp; int ldb;
  if (j < s1)      { bp = B0 + (size_t)brow * ld0 + j;        ldb = ld0; }
  else if (j < s2) { bp = B1 + (size_t)brow * ld1 + (j - s1); ldb = ld1; }
  else             { bp = B2 + (size_t)brow * ld2 + (j - s2); ldb = ld2; }
  const float* ap = A + (size_t)(m0 + arow) * K + acol;
  for (int k0 = 0; k0 < K; k0 += 8) {
    float4 av = *(const float4*)(ap + k0);
    float4 bv = *(const float4*)(bp);
    bp += (size_t)8 * ldb;
    As[acol + 0][arow] = av.x;
    As[acol + 1][arow] = av.y;
    As[acol + 2][arow] = av.z;
    As[acol + 3][arow] = av.w;
    *(float4*)&Bs[brow][bcol] = bv;
    __syncthreads();
#pragma unroll
    for (int kk = 0; kk < 8; kk++) {
      float a[8], b[8];
      *(float4*)&a[0] = *(const float4*)&As[kk][ty * 8];
      *(float4*)&a[4] = *(const float4*)&As[kk][ty * 8 + 4];
      *(float4*)&b[0] = *(const float4*)&Bs[kk][tx * 8];
      *(float4*)&b[4] = *(const float4*)&Bs[kk][tx * 8 + 4];
#pragma unroll
      for (int i = 0; i < 8; i++)
#pragma unroll
        for (int jj = 0; jj < 8; jj++)
          acc[i][jj] = fmaf(a[i], b[jj], acc[i][jj]);
    }
    __syncthreads();
  }
#pragma unroll
  for (int i = 0; i < 8; i++) {
    float* crow = C + (size_t)(m0 + ty * 8 + i) * N + n0 + tx * 8;
    *(float4*)crow = *(const float4*)&acc[i][0];
    *(float4*)(crow + 4) = *(const float4*)&acc[i][4];
  }
}

// ---------------- running means: ck = k - cummean(k), cv/mv for v ------------
// one block per (b,h); thread f owns one feature column, sequential over L.
__global__ __launch_bounds__(128)
void cummean_kernel(const float* __restrict__ proj,
                    float* __restrict__ ck, float* __restrict__ cv,
                    float* __restrict__ mv) {
  int bh = blockIdx.x;
  int b = bh / NH, h = bh % NH;
  int f = threadIdx.x;
  if (f >= F + DH) return;
  const float* base = proj + (size_t)b * L * NPROJ;
  float run = 0.f;
  if (f < F) {
    int off = 192 + h * F + f;
    float* ckb = ck + (size_t)bh * L * F + f;
    for (int l = 0; l < L; l++) {
      float val = base[(size_t)l * NPROJ + off];
      run += val;
      float mean = run / (float)(l + 1);
      ckb[(size_t)l * F] = val - mean;
    }
  } else {
    int d = f - F;
    int off = 384 + h * DH + d;
    float* cvb = cv + (size_t)bh * L * DH + d;
    float* mvb = mv + (size_t)bh * L * DH + d;
    for (int l = 0; l < L; l++) {
      float val = base[(size_t)l * NPROJ + off];
      run += val;
      float mean = run / (float)(l + 1);
      cvb[(size_t)l * DH] = val - mean;
      mvb[(size_t)l * DH] = mean;
    }
  }
}

// ---------------- causal scores + row sum-of-squares + qKV -------------------
// block = (b, h, 256-query tile); thread owns one query. p-tiles of 64 staged
// in LDS; all LDS reads are wave-uniform broadcasts (conflict-free).
__global__ __launch_bounds__(256)
void attn_kernel(const float* __restrict__ proj, const float* __restrict__ ck,
                 const float* __restrict__ cv, float* __restrict__ qkv,
                 float* __restrict__ rs2) {
  int bh = blockIdx.y;
  int b = bh / NH, h = bh % NH;
  int qtile = blockIdx.x;
  int q = qtile * 256 + threadIdx.x;
  __shared__ __align__(16) float cks[64][F];
  __shared__ __align__(16) float cvs[64][DH];
  float qv[F];
  {
    const float* qrow = proj + ((size_t)(b * L + q)) * NPROJ + h * F;
    *(float4*)&qv[0]  = *(const float4*)(qrow);
    *(float4*)&qv[4]  = *(const float4*)(qrow + 4);
    *(float4*)&qv[8]  = *(const float4*)(qrow + 8);
    *(float4*)&qv[12] = *(const float4*)(qrow + 12);
  }
  float acc[DH];
#pragma unroll
  for (int d = 0; d < DH; d++) acc[d] = 0.f;
  float s2 = 0.f;
  const float* ckb = ck + (size_t)bh * L * F;
  const float* cvb = cv + (size_t)bh * L * DH;
  int pend = qtile * 256 + 256;
  for (int p0 = 0; p0 < pend; p0 += 64) {
    int idx = threadIdx.x;
    ((float4*)cks)[idx] = ((const float4*)(ckb + (size_t)p0 * F))[idx];
#pragma unroll
    for (int r = 0; r < 4; r++)
      ((float4*)cvs)[idx + 256 * r] =
          ((const float4*)(cvb + (size_t)p0 * DH))[idx + 256 * r];
    __syncthreads();
    int pe = min(64, q + 1 - p0);
    for (int pp = 0; pp < pe; pp++) {
      const float* ckr = cks[pp];
      float sA = 0.f, sB = 0.f, sC = 0.f, sD = 0.f;
#pragma unroll
      for (int i = 0; i < 4; i++)  sA = fmaf(qv[i],      ckr[i],      sA);
#pragma unroll
      for (int i = 0; i < 4; i++)  sB = fmaf(qv[4 + i],  ckr[4 + i],  sB);
#pragma unroll
      for (int i = 0; i < 4; i++)  sC = fmaf(qv[8 + i],  ckr[8 + i],  sC);
#pragma unroll
      for (int i = 0; i < 4; i++)  sD = fmaf(qv[12 + i], ckr[12 + i], sD);
      float s = (sA + sB) + (sC + sD);
      s2 = fmaf(s, s, s2);
      const float4* cvr = (const float4*)cvs[pp];
#pragma unroll
      for (int d4 = 0; d4 < 16; d4++) {
        float4 vv = cvr[d4];
        acc[d4 * 4 + 0] = fmaf(s, vv.x, acc[d4 * 4 + 0]);
        acc[d4 * 4 + 1] = fmaf(s, vv.y, acc[d4 * 4 + 1]);
        acc[d4 * 4 + 2] = fmaf(s, vv.z, acc[d4 * 4 + 2]);
        acc[d4 * 4 + 3] = fmaf(s, vv.w, acc[d4 * 4 + 3]);
      }
    }
    __syncthreads();
  }
  float* qkvrow = qkv + ((size_t)bh * L + q) * DH;
#pragma unroll
  for (int d4 = 0; d4 < 16; d4++) {
    float4 o;
    o.x = acc[d4 * 4 + 0] * 0.125f;  // / sqrt(DH)
    o.y = acc[d4 * 4 + 1] * 0.125f;
    o.z = acc[d4 * 4 + 2] * 0.125f;
    o.w = acc[d4 * 4 + 3] * 0.125f;
    *(float4*)(qkvrow + d4 * 4) = o;
  }
  rs2[(size_t)bh * L + q] = s2 * (1.0f / 128.0f);  // * inv_2d
}

// ---------------- prefix-scan denominator + combine --------------------------
__global__ __launch_bounds__(256)
void finalize_kernel(const float* __restrict__ rs2, const float* __restrict__ qkv,
                     const float* __restrict__ mv, float* __restrict__ Y) {
  int bh = blockIdx.x;
  int b = bh / NH, h = bh % NH;
  __shared__ float denom[L];
  __shared__ float partial[256];
  int tid = threadIdx.x;
  const float* rs = rs2 + (size_t)bh * L;
  float vals[8];
  float run = 0.f;
#pragma unroll
  for (int i = 0; i < 8; i++) { run += rs[tid * 8 + i]; vals[i] = run; }
  partial[tid] = run;
  __syncthreads();
  for (int off = 1; off < 256; off <<= 1) {
    float add = (tid >= off) ? partial[tid - off] : 0.f;
    __syncthreads();
    partial[tid] += add;
    __syncthreads();
  }
  float base = (tid > 0) ? partial[tid - 1] : 0.f;
#pragma unroll
  for (int i = 0; i < 8; i++) {
    int l = tid * 8 + i;
    denom[l] = (float)(l + 1) + (vals[i] + base);
  }
  __syncthreads();
  const float* qk = qkv + (size_t)bh * L * DH;
  const float* mvb = mv + (size_t)bh * L * DH;
  for (int idx4 = tid; idx4 < L * 16; idx4 += 256) {
    int l = idx4 >> 4, d4 = idx4 & 15;
    float4 qv4 = *(const float4*)(qk + (size_t)l * DH + d4 * 4);
    float4 mv4 = *(const float4*)(mvb + (size_t)l * DH + d4 * 4);
    float inv = 1.0f / denom[l];
    float4 o;
    o.x = mv4.x + qv4.x * inv;
    o.y = mv4.y + qv4.y * inv;
    o.z = mv4.z + qv4.z * inv;
    o.w = mv4.w + qv4.w * inv;
    *(float4*)(Y + ((size_t)(b * L + l)) * DMODEL + h * DH + d4 * 4) = o;
  }
}

extern "C" void kernel_launch(void* const* d_in, const int* in_sizes, int n_in,
                              void* d_out, int out_size, void* d_ws, size_t ws_size,
                              hipStream_t stream) {
  const float* hs = (const float*)d_in[0];
  const float* Wq = (const float*)d_in[1];
  const float* Wk = (const float*)d_in[2];
  const float* Wv = (const float*)d_in[3];
  const float* Wo = (const float*)d_in[4];
  float* out = (float*)d_out;
  float* ws = (float*)d_ws;

  float* proj = ws;                               // 4096*1152 = 4718592
  float* Y    = ws;                               // alias: proj dead before K4
  float* ck   = ws + (size_t)4096 * 1152;         // 786432
  float* cv   = ck + (size_t)786432;              // 3145728
  float* mv   = cv + (size_t)3145728;             // 3145728
  float* qkv  = mv + (size_t)3145728;             // 3145728
  float* rs2  = qkv + (size_t)3145728;            // 49152
  // total ~57.2 MiB of d_ws

  dim3 g1(NPROJ / 128, (B * L) / 128);
  gemm_kernel<<<g1, 256, 0, stream>>>(hs, B * L, NPROJ, DMODEL,
                                      Wq, Wk, Wv, 192, 384, 192, 192, 768, proj);
  cummean_kernel<<<B * NH, 128, 0, stream>>>(proj, ck, cv, mv);
  dim3 g3(L / 256, B * NH);
  attn_kernel<<<g3, 256, 0, stream>>>(proj, ck, cv, qkv, rs2);
  finalize_kernel<<<B * NH, 256, 0, stream>>>(rs2, qkv, mv, Y);
  dim3 g5(DMODEL / 128, (B * L) / 128);
  gemm_kernel<<<g5, 256, 0, stream>>>(Y, B * L, DMODEL, DMODEL,
                                      Wo, Wo, Wo, DMODEL, DMODEL,
                                      768, 768, 768, out);
}

// Round 3
// 201.136 us; speedup vs baseline: 9.2397x; 9.2397x over previous
//
#include <hip/hip_runtime.h>
#include <hip/hip_bf16.h>
#include <stdint.h>

constexpr int B_ = 2, L_ = 2048, DM = 768, NH_ = 12, F_ = 16, DH_ = 64;
constexpr int NPROJ = 1152;

typedef __bf16 bf16x8 __attribute__((ext_vector_type(8)));
typedef __bf16 bf16x4 __attribute__((ext_vector_type(4)));
typedef float f32x4 __attribute__((ext_vector_type(4)));

#define GLOAD16(g, l)                                                        \
  __builtin_amdgcn_global_load_lds(                                          \
      (const __attribute__((address_space(1))) void*)(g),                    \
      (__attribute__((address_space(3))) void*)(l), 16, 0, 0)

__device__ __forceinline__ bf16x8 zero_bf8() {
  bf16x8 z;
#pragma unroll
  for (int j = 0; j < 8; j++) z[j] = (__bf16)0.0f;
  return z;
}

// ---------------- cast + weight transpose --------------------------------
__global__ __launch_bounds__(256)
void prep_cast(const float* __restrict__ hs, const float* __restrict__ Wq,
               const float* __restrict__ Wk, const float* __restrict__ Wv,
               const float* __restrict__ Wo, __bf16* __restrict__ hsb,
               __bf16* __restrict__ WqkvT, __bf16* __restrict__ WoT) {
  int idx = blockIdx.x * 256 + threadIdx.x;
  int stride = gridDim.x * 256;
  for (int i = idx; i < B_ * L_ * DM; i += stride) hsb[i] = (__bf16)hs[i];
  for (int i = idx; i < NPROJ * DM; i += stride) {
    int n = i / DM, k = i % DM;
    float v;
    if (n < 192)      v = Wq[(size_t)k * 192 + n];
    else if (n < 384) v = Wk[(size_t)k * 192 + (n - 192)];
    else              v = Wv[(size_t)k * 768 + (n - 384)];
    WqkvT[i] = (__bf16)v;
  }
  for (int i = idx; i < DM * DM; i += stride) {
    int n = i / DM, k = i % DM;
    WoT[i] = (__bf16)Wo[(size_t)k * DM + n];
  }
}

// ---------------- bf16 MFMA GEMM: C(MxN) = A(MxK) @ Bt(NxK)^T ------------
// 128x128 tile, BK=32, 4 waves each computing 64x64 (4x4 16x16 frags).
// mode 1: columns n<192 are the q-projection -> written bf16 to Qh.
__global__ __launch_bounds__(256)
void gemm_bf16(const __bf16* __restrict__ A, const __bf16* __restrict__ Bt,
               int M, int N, int K, float* __restrict__ C,
               __bf16* __restrict__ Qh, int mode) {
  __shared__ __align__(16) __bf16 Al[128 * 32];
  __shared__ __align__(16) __bf16 Bl[128 * 32];
  int tid = threadIdx.x;
  int m0 = blockIdx.y * 128, n0 = blockIdx.x * 128;
  int w = tid >> 6, l = tid & 63, lr = l & 15, lg = l >> 4;
  int wr = w >> 1, wc = w & 1;
  f32x4 acc[4][4] = {};
  const __bf16* Ab = A + (size_t)m0 * K;
  const __bf16* Bb = Bt + (size_t)n0 * K;
  for (int k0 = 0; k0 < K; k0 += 32) {
    __syncthreads();
#pragma unroll
    for (int i = 0; i < 2; i++) {
      int idx = i * 256 + tid;
      int row = idx >> 2, ch = idx & 3;
      GLOAD16(Ab + (size_t)row * K + k0 + ch * 8, &Al[idx * 8]);
    }
#pragma unroll
    for (int i = 0; i < 2; i++) {
      int idx = i * 256 + tid;
      int row = idx >> 2, ch = idx & 3;
      GLOAD16(Bb + (size_t)row * K + k0 + ch * 8, &Bl[idx * 8]);
    }
    asm volatile("s_waitcnt vmcnt(0)" ::: "memory");
    __syncthreads();
    bf16x8 af[4], bfr[4];
#pragma unroll
    for (int mi = 0; mi < 4; mi++)
      af[mi] = *(const bf16x8*)&Al[(wr * 64 + mi * 16 + lr) * 32 + lg * 8];
#pragma unroll
    for (int ni = 0; ni < 4; ni++)
      bfr[ni] = *(const bf16x8*)&Bl[(wc * 64 + ni * 16 + lr) * 32 + lg * 8];
#pragma unroll
    for (int mi = 0; mi < 4; mi++)
#pragma unroll
      for (int ni = 0; ni < 4; ni++)
        acc[mi][ni] = __builtin_amdgcn_mfma_f32_16x16x32_bf16(
            af[mi], bfr[ni], acc[mi][ni], 0, 0, 0);
  }
#pragma unroll
  for (int mi = 0; mi < 4; mi++)
#pragma unroll
    for (int ni = 0; ni < 4; ni++) {
      int n = n0 + wc * 64 + ni * 16 + lr;
#pragma unroll
      for (int r = 0; r < 4; r++) {
        int m = m0 + wr * 64 + mi * 16 + lg * 4 + r;
        float v = acc[mi][ni][r];
        if (mode == 1 && n < 192) {
          int h = n >> 4, f = n & 15;
          int b = m >> 11, ll = m & 2047;
          Qh[((size_t)(b * NH_ + h) * L_ + ll) * F_ + f] = (__bf16)v;
        } else {
          C[(size_t)m * N + n] = v;
        }
      }
    }
}

// ---------------- per-column cumulative-mean scan ------------------------
// block = (bh*80 + c): c<16 -> k column, else v column d=c-16.
__global__ __launch_bounds__(256)
void scan_kernel(const float* __restrict__ proj, __bf16* __restrict__ CKh,
                 __bf16* __restrict__ CVT, float* __restrict__ MV) {
  int blk = blockIdx.x;
  int bh = blk / 80, c = blk % 80;
  int b = bh / NH_, h = bh % NH_;
  int t = threadIdx.x;
  int off = (c < 16) ? (192 + h * 16 + c) : (384 + h * 64 + (c - 16));
  const float* src = proj + (size_t)b * L_ * NPROJ + off;
  float v[8];
  float run = 0.f;
#pragma unroll
  for (int i = 0; i < 8; i++) {
    v[i] = src[(size_t)(t * 8 + i) * NPROJ];
    run += v[i];
  }
  __shared__ float part[256];
  part[t] = run;
  __syncthreads();
  for (int o = 1; o < 256; o <<= 1) {
    float add = (t >= o) ? part[t - o] : 0.f;
    __syncthreads();
    part[t] += add;
    __syncthreads();
  }
  float run2 = (t > 0) ? part[t - 1] : 0.f;
  if (c < 16) {
#pragma unroll
    for (int i = 0; i < 8; i++) {
      run2 += v[i];
      int ll = t * 8 + i;
      float mean = run2 / (float)(ll + 1);
      CKh[((size_t)bh * L_ + ll) * F_ + c] = (__bf16)(v[i] - mean);
    }
  } else {
    int d = c - 16;
#pragma unroll
    for (int i = 0; i < 8; i++) {
      run2 += v[i];
      int ll = t * 8 + i;
      float mean = run2 / (float)(ll + 1);
      CVT[((size_t)bh * DH_ + d) * L_ + ll] = (__bf16)(v[i] - mean);
      MV[((size_t)bh * L_ + ll) * DH_ + d] = mean;
    }
  }
}

// ---------------- flash-style MFMA attention core ------------------------
// block = (bh, qtile of 128). 4 waves, wave w owns q rows [w*32, w*32+32).
__global__ __launch_bounds__(256)
void attn_mfma(const __bf16* __restrict__ Qh, const __bf16* __restrict__ CKh,
               const __bf16* __restrict__ CVT, float* __restrict__ qkv,
               float* __restrict__ rs2) {
  __shared__ __align__(16) __bf16 CKl[128 * 24];   // padded rows (16->24)
  __shared__ __align__(16) __bf16 CVl[64 * 136];   // d-major, padded 128->136
  __shared__ __align__(16) __bf16 Pl[128 * 136];   // q-major, padded
  int bh = blockIdx.y;
  int qt = (gridDim.x - 1) - blockIdx.x;  // big tiles scheduled first
  int q0 = qt * 128;
  int tid = threadIdx.x;
  int w = tid >> 6, l = tid & 63, lr = l & 15, lg = l >> 4;

  bf16x8 qa[2];
#pragma unroll
  for (int mi = 0; mi < 2; mi++) {
    bf16x8 z = zero_bf8();
    if (lg < 2)
      z = *(const bf16x8*)(Qh + ((size_t)bh * L_ + q0 + w * 32 + mi * 16 + lr) * F_ + lg * 8);
    qa[mi] = z;
  }
  f32x4 pv[2][4] = {};
  float s2[2][4] = {};

  for (int pt = 0; pt <= qt; pt++) {
    int p0 = pt * 128;
    __syncthreads();
    {  // stage CK tile (128 x 16)
      int row = tid >> 1, half = tid & 1;
      bf16x8 d = *(const bf16x8*)(CKh + ((size_t)bh * L_ + p0 + row) * F_ + half * 8);
      *(bf16x8*)&CKl[row * 24 + half * 8] = d;
    }
#pragma unroll
    for (int i = 0; i < 4; i++) {  // stage CV^T tile (64 x 128)
      int idx = i * 256 + tid;
      int dd = idx >> 4, seg = idx & 15;
      bf16x8 dta = *(const bf16x8*)(CVT + ((size_t)bh * DH_ + dd) * L_ + p0 + seg * 8);
      *(bf16x8*)&CVl[dd * 136 + seg * 8] = dta;
    }
    __syncthreads();

    // S = Q @ CK^T  (K=16 zero-padded to 32)
    f32x4 s[2][8];
#pragma unroll
    for (int ni = 0; ni < 8; ni++) {
      bf16x8 bfv = *(const bf16x8*)&CKl[(ni * 16 + lr) * 24 + (lg & 1) * 8];
      if (lg >= 2) bfv = zero_bf8();
#pragma unroll
      for (int mi = 0; mi < 2; mi++) {
        f32x4 zc = {0.f, 0.f, 0.f, 0.f};
        s[mi][ni] = __builtin_amdgcn_mfma_f32_16x16x32_bf16(qa[mi], bfv, zc, 0, 0, 0);
      }
    }

    // mask (diagonal only) + s^2 accum + write P (bf16) to LDS
    bool diag = (pt == qt);
#pragma unroll
    for (int mi = 0; mi < 2; mi++)
#pragma unroll
      for (int ni = 0; ni < 8; ni++)
#pragma unroll
        for (int r = 0; r < 4; r++) {
          int qrow = w * 32 + mi * 16 + lg * 4 + r;
          int prow = ni * 16 + lr;
          float sv = s[mi][ni][r];
          if (diag && prow > qrow) sv = 0.f;
          s2[mi][r] += sv * sv;
          Pl[qrow * 136 + prow] = (__bf16)sv;
        }

    // PV: D(32x64 per wave) += P(32x128) @ CV(128x64); same-wave LDS reuse
#pragma unroll
    for (int ks = 0; ks < 4; ks++) {
      bf16x8 pa[2], bv[4];
#pragma unroll
      for (int mi = 0; mi < 2; mi++)
        pa[mi] = *(const bf16x8*)&Pl[(w * 32 + mi * 16 + lr) * 136 + ks * 32 + lg * 8];
#pragma unroll
      for (int nd = 0; nd < 4; nd++)
        bv[nd] = *(const bf16x8*)&CVl[(nd * 16 + lr) * 136 + ks * 32 + lg * 8];
#pragma unroll
      for (int mi = 0; mi < 2; mi++)
#pragma unroll
        for (int nd = 0; nd < 4; nd++)
          pv[mi][nd] = __builtin_amdgcn_mfma_f32_16x16x32_bf16(
              pa[mi], bv[nd], pv[mi][nd], 0, 0, 0);
    }
  }

  // reduce s^2 across the 16 lanes sharing lg, write rs2
#pragma unroll
  for (int mi = 0; mi < 2; mi++)
#pragma unroll
    for (int r = 0; r < 4; r++) {
      float v = s2[mi][r];
      v += __shfl_xor(v, 1, 64);
      v += __shfl_xor(v, 2, 64);
      v += __shfl_xor(v, 4, 64);
      v += __shfl_xor(v, 8, 64);
      s2[mi][r] = v;
    }
  if (lr == 0) {
#pragma unroll
    for (int mi = 0; mi < 2; mi++)
#pragma unroll
      for (int r = 0; r < 4; r++) {
        int q = q0 + w * 32 + mi * 16 + lg * 4 + r;
        rs2[(size_t)bh * L_ + q] = s2[mi][r] * (1.0f / 128.0f);
      }
  }
#pragma unroll
  for (int mi = 0; mi < 2; mi++)
#pragma unroll
    for (int nd = 0; nd < 4; nd++)
#pragma unroll
      for (int r = 0; r < 4; r++) {
        int q = q0 + w * 32 + mi * 16 + lg * 4 + r;
        qkv[((size_t)bh * L_ + q) * DH_ + nd * 16 + lr] = pv[mi][nd][r] * 0.125f;
      }
}

// ---------------- denominator scan ---------------------------------------
__global__ __launch_bounds__(256)
void denom_kernel(const float* __restrict__ rs2, float* __restrict__ denom) {
  int bh = blockIdx.x;
  int t = threadIdx.x;
  const float* rs = rs2 + (size_t)bh * L_;
  float vals[8];
  float run = 0.f;
#pragma unroll
  for (int i = 0; i < 8; i++) { run += rs[t * 8 + i]; vals[i] = run; }
  __shared__ float part[256];
  part[t] = run;
  __syncthreads();
  for (int o = 1; o < 256; o <<= 1) {
    float add = (t >= o) ? part[t - o] : 0.f;
    __syncthreads();
    part[t] += add;
    __syncthreads();
  }
  float base = (t > 0) ? part[t - 1] : 0.f;
#pragma unroll
  for (int i = 0; i < 8; i++) {
    int ll = t * 8 + i;
    denom[(size_t)bh * L_ + ll] = (float)(ll + 1) + base + vals[i];
  }
}

// ---------------- combine: Y = mv + qkv/denom, bf16 ----------------------
__global__ __launch_bounds__(256)
void combine_kernel(const float* __restrict__ qkv, const float* __restrict__ MV,
                    const float* __restrict__ denom, __bf16* __restrict__ Yb) {
  int bh = blockIdx.y, lt = blockIdx.x;
  int b = bh / NH_, h = bh % NH_;
  int t = threadIdx.x;
  int l0 = lt * 256;
  __shared__ float dinv[256];
  dinv[t] = 1.0f / denom[(size_t)bh * L_ + l0 + t];
  __syncthreads();
  for (int it = 0; it < 16; it++) {
    int v = it * 256 + t;
    int ll = v >> 4, d4 = v & 15;
    const float4 q4 = *(const float4*)(qkv + ((size_t)bh * L_ + l0 + ll) * DH_ + d4 * 4);
    const float4 m4 = *(const float4*)(MV + ((size_t)bh * L_ + l0 + ll) * DH_ + d4 * 4);
    float iv = dinv[ll];
    bf16x4 o;
    o[0] = (__bf16)(m4.x + q4.x * iv);
    o[1] = (__bf16)(m4.y + q4.y * iv);
    o[2] = (__bf16)(m4.z + q4.z * iv);
    o[3] = (__bf16)(m4.w + q4.w * iv);
    *(bf16x4*)(Yb + ((size_t)(b * L_ + l0 + ll)) * DM + h * DH_ + d4 * 4) = o;
  }
}

extern "C" void kernel_launch(void* const* d_in, const int* in_sizes, int n_in,
                              void* d_out, int out_size, void* d_ws, size_t ws_size,
                              hipStream_t stream) {
  const float* hs = (const float*)d_in[0];
  const float* Wq = (const float*)d_in[1];
  const float* Wk = (const float*)d_in[2];
  const float* Wv = (const float*)d_in[3];
  const float* Wo = (const float*)d_in[4];
  float* out = (float*)d_out;
  char* w = (char*)d_ws;

  __bf16* hsb   = (__bf16*)(w);                      // 6,291,456
  __bf16* WqkvT = (__bf16*)(w + 6291456);            // 1,769,472
  __bf16* WoT   = (__bf16*)(w + 8060928);            // 1,179,648
  float*  proj  = (float*)(w + 9240576);             // 18,874,368
  __bf16* Yb    = (__bf16*)(w + 9240576);            // alias: proj[0..6.29MB)
  float*  qkvb  = (float*)(w + 9240576 + 6291456);   // alias: proj[6.29..18.87MB)
  __bf16* Qh    = (__bf16*)(w + 28114944);           // 1,572,864
  __bf16* CKh   = (__bf16*)(w + 29687808);           // 1,572,864
  __bf16* CVTg  = (__bf16*)(w + 31260672);           // 6,291,456
  float*  MV    = (float*)(w + 37552128);            // 12,582,912
  float*  rs2   = (float*)(w + 50135040);            // 196,608
  float*  denom = (float*)(w + 50331648);            // 196,608

  prep_cast<<<1024, 256, 0, stream>>>(hs, Wq, Wk, Wv, Wo, hsb, WqkvT, WoT);
  dim3 g1(NPROJ / 128, (B_ * L_) / 128);
  gemm_bf16<<<g1, 256, 0, stream>>>(hsb, WqkvT, B_ * L_, NPROJ, DM, proj, Qh, 1);
  scan_kernel<<<24 * 80, 256, 0, stream>>>(proj, CKh, CVTg, MV);
  dim3 g3(L_ / 128, 24);
  attn_mfma<<<g3, 256, 0, stream>>>(Qh, CKh, CVTg, qkvb, rs2);
  denom_kernel<<<24, 256, 0, stream>>>(rs2, denom);
  dim3 g5(8, 24);
  combine_kernel<<<g5, 256, 0, stream>>>(qkvb, MV, denom, Yb);
  dim3 g6(DM / 128, (B_ * L_) / 128);
  gemm_bf16<<<g6, 256, 0, stream>>>(Yb, WoT, B_ * L_, DM, DM, out, nullptr, 0);
}

// Round 4
// 165.564 us; speedup vs baseline: 11.2248x; 1.2149x over previous
//
#include <hip/hip_runtime.h>
#include <hip/hip_bf16.h>
#include <stdint.h>

constexpr int B_ = 2, L_ = 2048, DM = 768, NH_ = 12, F_ = 16, DH_ = 64;
constexpr int NPROJ = 1152;
constexpr int CH = 64, NCH = L_ / CH;  // scan chunking

typedef __bf16 bf16x8 __attribute__((ext_vector_type(8)));
typedef __bf16 bf16x4 __attribute__((ext_vector_type(4)));
typedef float f32x4 __attribute__((ext_vector_type(4)));

#define GLOAD16(g, l)                                                        \
  __builtin_amdgcn_global_load_lds(                                          \
      (const __attribute__((address_space(1))) void*)(g),                    \
      (__attribute__((address_space(3))) void*)(l), 16, 0, 0)

__device__ __forceinline__ bf16x8 zero_bf8() {
  bf16x8 z;
#pragma unroll
  for (int j = 0; j < 8; j++) z[j] = (__bf16)0.0f;
  return z;
}

// ---------------- cast + weight transpose --------------------------------
__global__ __launch_bounds__(256)
void prep_cast(const float* __restrict__ hs, const float* __restrict__ Wq,
               const float* __restrict__ Wk, const float* __restrict__ Wv,
               const float* __restrict__ Wo, __bf16* __restrict__ hsb,
               __bf16* __restrict__ WqkvT, __bf16* __restrict__ WoT) {
  int idx = blockIdx.x * 256 + threadIdx.x;
  int stride = gridDim.x * 256;
  for (int i = idx; i < B_ * L_ * DM; i += stride) hsb[i] = (__bf16)hs[i];
  for (int i = idx; i < NPROJ * DM; i += stride) {
    int n = i / DM, k = i % DM;
    float v;
    if (n < 192)      v = Wq[(size_t)k * 192 + n];
    else if (n < 384) v = Wk[(size_t)k * 192 + (n - 192)];
    else              v = Wv[(size_t)k * 768 + (n - 384)];
    WqkvT[i] = (__bf16)v;
  }
  for (int i = idx; i < DM * DM; i += stride) {
    int n = i / DM, k = i % DM;
    WoT[i] = (__bf16)Wo[(size_t)k * DM + n];
  }
}

// ---------------- bf16 MFMA GEMM: C(MxN) = A(MxK) @ Bt(NxK)^T ------------
__global__ __launch_bounds__(256)
void gemm_bf16(const __bf16* __restrict__ A, const __bf16* __restrict__ Bt,
               int M, int N, int K, float* __restrict__ C,
               __bf16* __restrict__ Qh, int mode) {
  __shared__ __align__(16) __bf16 Al[128 * 32];
  __shared__ __align__(16) __bf16 Bl[128 * 32];
  int tid = threadIdx.x;
  int m0 = blockIdx.y * 128, n0 = blockIdx.x * 128;
  int w = tid >> 6, l = tid & 63, lr = l & 15, lg = l >> 4;
  int wr = w >> 1, wc = w & 1;
  f32x4 acc[4][4] = {};
  const __bf16* Ab = A + (size_t)m0 * K;
  const __bf16* Bb = Bt + (size_t)n0 * K;
  for (int k0 = 0; k0 < K; k0 += 32) {
    __syncthreads();
#pragma unroll
    for (int i = 0; i < 2; i++) {
      int idx = i * 256 + tid;
      int row = idx >> 2, ch = idx & 3;
      GLOAD16(Ab + (size_t)row * K + k0 + ch * 8, &Al[idx * 8]);
    }
#pragma unroll
    for (int i = 0; i < 2; i++) {
      int idx = i * 256 + tid;
      int row = idx >> 2, ch = idx & 3;
      GLOAD16(Bb + (size_t)row * K + k0 + ch * 8, &Bl[idx * 8]);
    }
    asm volatile("s_waitcnt vmcnt(0)" ::: "memory");
    __syncthreads();
    bf16x8 af[4], bfr[4];
#pragma unroll
    for (int mi = 0; mi < 4; mi++)
      af[mi] = *(const bf16x8*)&Al[(wr * 64 + mi * 16 + lr) * 32 + lg * 8];
#pragma unroll
    for (int ni = 0; ni < 4; ni++)
      bfr[ni] = *(const bf16x8*)&Bl[(wc * 64 + ni * 16 + lr) * 32 + lg * 8];
#pragma unroll
    for (int mi = 0; mi < 4; mi++)
#pragma unroll
      for (int ni = 0; ni < 4; ni++)
        acc[mi][ni] = __builtin_amdgcn_mfma_f32_16x16x32_bf16(
            af[mi], bfr[ni], acc[mi][ni], 0, 0, 0);
  }
#pragma unroll
  for (int mi = 0; mi < 4; mi++)
#pragma unroll
    for (int ni = 0; ni < 4; ni++) {
      int n = n0 + wc * 64 + ni * 16 + lr;
#pragma unroll
      for (int r = 0; r < 4; r++) {
        int m = m0 + wr * 64 + mi * 16 + lg * 4 + r;
        float v = acc[mi][ni][r];
        if (mode == 1 && n < 192) {
          int h = n >> 4, f = n & 15;
          int b = m >> 11, ll = m & 2047;
          Qh[((size_t)(b * NH_ + h) * L_ + ll) * F_ + f] = (__bf16)v;
        } else {
          C[(size_t)m * N + n] = v;
        }
      }
    }
}

// ---------------- chunked column sums: csum[bh][ch][80] ------------------
__global__ __launch_bounds__(128)
void scan_sum(const float* __restrict__ proj, float* __restrict__ csum) {
  int bh = blockIdx.y, ch = blockIdx.x;
  int b = bh / NH_, h = bh % NH_;
  int c = threadIdx.x;
  if (c >= 80) return;
  int off = (c < 16) ? (192 + h * 16 + c) : (384 + h * 64 + (c - 16));
  const float* src = proj + ((size_t)b * L_ + ch * CH) * NPROJ + off;
  float s = 0.f;
#pragma unroll 8
  for (int r = 0; r < CH; r++) s += src[(size_t)r * NPROJ];
  csum[((size_t)bh * NCH + ch) * 80 + c] = s;
}

// ---------------- apply: prefix base + in-chunk mean scan ----------------
// writes CK (bf16), CV^T (bf16, d-major), and running-mean directly into Yb.
__global__ __launch_bounds__(128)
void scan_apply(const float* __restrict__ proj, const float* __restrict__ csum,
                __bf16* __restrict__ CKh, __bf16* __restrict__ CVT,
                __bf16* __restrict__ Yb) {
  int bh = blockIdx.y, ch = blockIdx.x;
  int b = bh / NH_, h = bh % NH_;
  int c = threadIdx.x;
  if (c >= 80) return;
  int off = (c < 16) ? (192 + h * 16 + c) : (384 + h * 64 + (c - 16));
  const float* src = proj + ((size_t)b * L_ + ch * CH) * NPROJ + off;
  float run = 0.f;
  for (int j = 0; j < ch; j++) run += csum[((size_t)bh * NCH + j) * 80 + c];
  if (c < 16) {
    __bf16* ckp = CKh + ((size_t)bh * L_ + ch * CH) * F_ + c;
    for (int r = 0; r < CH; r++) {
      float val = src[(size_t)r * NPROJ];
      run += val;
      float mean = run / (float)(ch * CH + r + 1);
      ckp[(size_t)r * F_] = (__bf16)(val - mean);
    }
  } else {
    int d = c - 16;
    __bf16* cvp = CVT + ((size_t)bh * DH_ + d) * L_ + ch * CH;
    __bf16* yp = Yb + ((size_t)(b * L_ + ch * CH)) * DM + h * DH_ + d;
    for (int r = 0; r < CH; r++) {
      float val = src[(size_t)r * NPROJ];
      run += val;
      float mean = run / (float)(ch * CH + r + 1);
      cvp[r] = (__bf16)(val - mean);
      yp[(size_t)r * DM] = (__bf16)mean;
    }
  }
}

// ---------------- flash-style MFMA attention core ------------------------
__global__ __launch_bounds__(256)
void attn_mfma(const __bf16* __restrict__ Qh, const __bf16* __restrict__ CKh,
               const __bf16* __restrict__ CVT, __bf16* __restrict__ qkv,
               float* __restrict__ rs2) {
  __shared__ __align__(16) __bf16 CKl[128 * 24];   // padded rows (16->24)
  __shared__ __align__(16) __bf16 CVl[64 * 136];   // d-major, padded 128->136
  __shared__ __align__(16) __bf16 Pl[128 * 136];   // q-major, padded
  int bh = blockIdx.y;
  int qt = (gridDim.x - 1) - blockIdx.x;  // big tiles scheduled first
  int q0 = qt * 128;
  int tid = threadIdx.x;
  int w = tid >> 6, l = tid & 63, lr = l & 15, lg = l >> 4;

  bf16x8 qa[2];
#pragma unroll
  for (int mi = 0; mi < 2; mi++) {
    bf16x8 z = zero_bf8();
    if (lg < 2)
      z = *(const bf16x8*)(Qh + ((size_t)bh * L_ + q0 + w * 32 + mi * 16 + lr) * F_ + lg * 8);
    qa[mi] = z;
  }
  f32x4 pv[2][4] = {};
  float s2[2][4] = {};

  for (int pt = 0; pt <= qt; pt++) {
    int p0 = pt * 128;
    __syncthreads();
    {  // stage CK tile (128 x 16)
      int row = tid >> 1, half = tid & 1;
      bf16x8 d = *(const bf16x8*)(CKh + ((size_t)bh * L_ + p0 + row) * F_ + half * 8);
      *(bf16x8*)&CKl[row * 24 + half * 8] = d;
    }
#pragma unroll
    for (int i = 0; i < 4; i++) {  // stage CV^T tile (64 x 128)
      int idx = i * 256 + tid;
      int dd = idx >> 4, seg = idx & 15;
      bf16x8 dta = *(const bf16x8*)(CVT + ((size_t)bh * DH_ + dd) * L_ + p0 + seg * 8);
      *(bf16x8*)&CVl[dd * 136 + seg * 8] = dta;
    }
    __syncthreads();

    // S = Q @ CK^T  (K=16 zero-padded to 32)
    f32x4 s[2][8];
#pragma unroll
    for (int ni = 0; ni < 8; ni++) {
      bf16x8 bfv = *(const bf16x8*)&CKl[(ni * 16 + lr) * 24 + (lg & 1) * 8];
      if (lg >= 2) bfv = zero_bf8();
#pragma unroll
      for (int mi = 0; mi < 2; mi++) {
        f32x4 zc = {0.f, 0.f, 0.f, 0.f};
        s[mi][ni] = __builtin_amdgcn_mfma_f32_16x16x32_bf16(qa[mi], bfv, zc, 0, 0, 0);
      }
    }

    // mask (diagonal only) + s^2 accum + write P (bf16) to LDS
    bool diag = (pt == qt);
#pragma unroll
    for (int mi = 0; mi < 2; mi++)
#pragma unroll
      for (int ni = 0; ni < 8; ni++)
#pragma unroll
        for (int r = 0; r < 4; r++) {
          int qrow = w * 32 + mi * 16 + lg * 4 + r;
          int prow = ni * 16 + lr;
          float sv = s[mi][ni][r];
          if (diag && prow > qrow) sv = 0.f;
          s2[mi][r] += sv * sv;
          Pl[qrow * 136 + prow] = (__bf16)sv;
        }

    // PV: D(32x64 per wave) += P(32x128) @ CV(128x64)
#pragma unroll
    for (int ks = 0; ks < 4; ks++) {
      bf16x8 pa[2], bv[4];
#pragma unroll
      for (int mi = 0; mi < 2; mi++)
        pa[mi] = *(const bf16x8*)&Pl[(w * 32 + mi * 16 + lr) * 136 + ks * 32 + lg * 8];
#pragma unroll
      for (int nd = 0; nd < 4; nd++)
        bv[nd] = *(const bf16x8*)&CVl[(nd * 16 + lr) * 136 + ks * 32 + lg * 8];
#pragma unroll
      for (int mi = 0; mi < 2; mi++)
#pragma unroll
        for (int nd = 0; nd < 4; nd++)
          pv[mi][nd] = __builtin_amdgcn_mfma_f32_16x16x32_bf16(
              pa[mi], bv[nd], pv[mi][nd], 0, 0, 0);
    }
  }

  // reduce s^2 across the 16 lanes sharing lg, write rs2
#pragma unroll
  for (int mi = 0; mi < 2; mi++)
#pragma unroll
    for (int r = 0; r < 4; r++) {
      float v = s2[mi][r];
      v += __shfl_xor(v, 1, 64);
      v += __shfl_xor(v, 2, 64);
      v += __shfl_xor(v, 4, 64);
      v += __shfl_xor(v, 8, 64);
      s2[mi][r] = v;
    }
  if (lr == 0) {
#pragma unroll
    for (int mi = 0; mi < 2; mi++)
#pragma unroll
      for (int r = 0; r < 4; r++) {
        int q = q0 + w * 32 + mi * 16 + lg * 4 + r;
        rs2[(size_t)bh * L_ + q] = s2[mi][r] * (1.0f / 128.0f);
      }
  }
#pragma unroll
  for (int mi = 0; mi < 2; mi++)
#pragma unroll
    for (int nd = 0; nd < 4; nd++)
#pragma unroll
      for (int r = 0; r < 4; r++) {
        int q = q0 + w * 32 + mi * 16 + lg * 4 + r;
        qkv[((size_t)bh * L_ + q) * DH_ + nd * 16 + lr] =
            (__bf16)(pv[mi][nd][r] * 0.125f);
      }
}

// ---------------- denominator scan ---------------------------------------
__global__ __launch_bounds__(256)
void denom_kernel(const float* __restrict__ rs2, float* __restrict__ denom) {
  int bh = blockIdx.x;
  int t = threadIdx.x;
  const float* rs = rs2 + (size_t)bh * L_;
  float vals[8];
  float run = 0.f;
#pragma unroll
  for (int i = 0; i < 8; i++) { run += rs[t * 8 + i]; vals[i] = run; }
  __shared__ float part[256];
  part[t] = run;
  __syncthreads();
  for (int o = 1; o < 256; o <<= 1) {
    float add = (t >= o) ? part[t - o] : 0.f;
    __syncthreads();
    part[t] += add;
    __syncthreads();
  }
  float base = (t > 0) ? part[t - 1] : 0.f;
#pragma unroll
  for (int i = 0; i < 8; i++) {
    int ll = t * 8 + i;
    denom[(size_t)bh * L_ + ll] = (float)(ll + 1) + base + vals[i];
  }
}

// ---------------- combine: Yb += qkv/denom (in place, bf16) --------------
__global__ __launch_bounds__(256)
void combine_kernel(const __bf16* __restrict__ qkv, const float* __restrict__ denom,
                    __bf16* __restrict__ Yb) {
  int bh = blockIdx.y, lt = blockIdx.x;
  int b = bh / NH_, h = bh % NH_;
  int t = threadIdx.x;
  int l0 = lt * 256;
  __shared__ float dinv[256];
  dinv[t] = 1.0f / denom[(size_t)bh * L_ + l0 + t];
  __syncthreads();
#pragma unroll
  for (int it = 0; it < 8; it++) {
    int v = it * 256 + t;
    int ll = v >> 3, d8 = v & 7;
    bf16x8 q8 = *(const bf16x8*)(qkv + ((size_t)bh * L_ + l0 + ll) * DH_ + d8 * 8);
    __bf16* yp = Yb + ((size_t)(b * L_ + l0 + ll)) * DM + h * DH_ + d8 * 8;
    bf16x8 y8 = *(const bf16x8*)yp;
    float iv = dinv[ll];
#pragma unroll
    for (int j = 0; j < 8; j++)
      y8[j] = (__bf16)((float)y8[j] + (float)q8[j] * iv);
    *(bf16x8*)yp = y8;
  }
}

extern "C" void kernel_launch(void* const* d_in, const int* in_sizes, int n_in,
                              void* d_out, int out_size, void* d_ws, size_t ws_size,
                              hipStream_t stream) {
  const float* hs = (const float*)d_in[0];
  const float* Wq = (const float*)d_in[1];
  const float* Wk = (const float*)d_in[2];
  const float* Wv = (const float*)d_in[3];
  const float* Wo = (const float*)d_in[4];
  float* out = (float*)d_out;
  char* w = (char*)d_ws;

  __bf16* hsb   = (__bf16*)(w);                      // 6,291,456
  __bf16* WqkvT = (__bf16*)(w + 6291456);            // 1,769,472
  __bf16* WoT   = (__bf16*)(w + 8060928);            // 1,179,648
  float*  proj  = (float*)(w + 9240576);             // 18,874,368
  __bf16* qkvb  = (__bf16*)(w + 28114944);           // 6,291,456
  __bf16* Qh    = (__bf16*)(w + 34406400);           // 1,572,864
  __bf16* CKh   = (__bf16*)(w + 35979264);           // 1,572,864
  __bf16* CVTg  = (__bf16*)(w + 37552128);           // 6,291,456
  __bf16* Yb    = (__bf16*)(w + 43843584);           // 6,291,456
  float*  rs2   = (float*)(w + 50135040);            // 98,304
  float*  denom = (float*)(w + 50233344);            // 98,304
  float*  csum  = (float*)(w + 50331648);            // 245,760
  // total ~50.6 MiB

  prep_cast<<<1024, 256, 0, stream>>>(hs, Wq, Wk, Wv, Wo, hsb, WqkvT, WoT);
  dim3 g1(NPROJ / 128, (B_ * L_) / 128);
  gemm_bf16<<<g1, 256, 0, stream>>>(hsb, WqkvT, B_ * L_, NPROJ, DM, proj, Qh, 1);
  dim3 gs(NCH, B_ * NH_);
  scan_sum<<<gs, 128, 0, stream>>>(proj, csum);
  scan_apply<<<gs, 128, 0, stream>>>(proj, csum, CKh, CVTg, Yb);
  dim3 g3(L_ / 128, 24);
  attn_mfma<<<g3, 256, 0, stream>>>(Qh, CKh, CVTg, qkvb, rs2);
  denom_kernel<<<24, 256, 0, stream>>>(rs2, denom);
  dim3 g5(8, 24);
  combine_kernel<<<g5, 256, 0, stream>>>(qkvb, denom, Yb);
  dim3 g6(DM / 128, (B_ * L_) / 128);
  gemm_bf16<<<g6, 256, 0, stream>>>(Yb, WoT, B_ * L_, DM, DM, out, nullptr, 0);
}